// Round 7
// baseline (497.323 us; speedup 1.0000x reference)
//
#include <hip/hip_runtime.h>
#include <stdint.h>

// ---------------------------------------------------------------------------
// SparseResUQueryNet: bitmap+rank sparse conv -> time max-pool -> sparse conv
//
// Round-7: round-6 + spatially-sorted query processing.
//   hist_ent[2^23] uint2: .x = existence bits for 32 keys, .y = exclusive rank.
//     key rank == row index (hcoords sorted by packed key) -> hf[rank].
//   pool_ent[2^20] uint2: same for pool keys; rank == dense pooled slot.
//   pooled: per slot 16 x u32 = 32 transformed-bf16 u16s (monotone, 0 = -inf).
//   Query path: bucket-sort points by qk>>11 (16384 buckets) so consecutive
//   half-waves probe the same few-KB pool_ent region (L1/L2-hot instead of
//   thrashing the 8.4MB array across random lines). qscatter also writes the
//   4-float head row (sequential-p pts reads).
// ---------------------------------------------------------------------------

#define TPB 256
#define SCAN_WPT 8
#define QBUCKETS 16384
typedef unsigned long long u64;
typedef unsigned int u32;
typedef unsigned short u16;

// f32 -> RNE bf16 -> monotone u16 (order-preserving; 0 is below all reals)
__device__ __forceinline__ u32 trans16(float x) {
    u32 b = __float_as_uint(x);
    u32 bf = (b + 0x7FFFu + ((b >> 16) & 1u)) >> 16;
    return ((bf & 0x8000u) ? (~bf) : (bf | 0x8000u)) & 0xFFFFu;
}
__device__ __forceinline__ float detrans16(u32 u) {
    u32 orig = (u & 0x8000u) ? (u & 0x7FFFu) : ((~u) & 0xFFFFu);
    return __uint_as_float(orig << 16);
}

// K1: set existence bits; second pool contributor marks multi ----------------
__global__ void build_bitmaps_kernel(const int4* __restrict__ hc,
                                     const int* __restrict__ hb,
                                     int n,
                                     uint2* __restrict__ hist_ent,
                                     uint2* __restrict__ pool_ent,
                                     u32* __restrict__ multi_bm) {
    int j = blockIdx.x * blockDim.x + threadIdx.x;
    if (j >= n) return;
    int4 c = hc[j];                                   // (t,x,y,z)
    int key = ((c.x * 256 + c.y) * 256 + c.z) * 256 + c.w;
    atomicOr(&hist_ent[key >> 5].x, 1u << (key & 31));
    int pk = ((hb[j] * 256 + c.y) * 256 + c.z) * 256 + c.w;
    u32 bit = 1u << (pk & 31);
    u32 old = atomicOr(&pool_ent[pk >> 5].x, bit);
    if (old & bit) atomicOr(&multi_bm[pk >> 5], bit); // >=2 contributors
}

// scan stage 1: per-block popcount sums --------------------------------------
__global__ void scan_sum_kernel(const uint2* __restrict__ ent, u32* __restrict__ bsum) {
    __shared__ u32 s[TPB];
    int t = threadIdx.x;
    size_t base = ((size_t)blockIdx.x * TPB + t) * SCAN_WPT;
    u32 acc = 0;
#pragma unroll
    for (int i = 0; i < SCAN_WPT; i++) acc += __popc(ent[base + i].x);
    s[t] = acc; __syncthreads();
    for (int off = TPB / 2; off > 0; off >>= 1) {
        if (t < off) s[t] += s[t + off];
        __syncthreads();
    }
    if (t == 0) bsum[blockIdx.x] = s[0];
}

// scan stage 2: exclusive scan of block sums (count <= 4096), one block ------
__global__ void scan_partials_kernel(u32* __restrict__ bsum, int count) {
    __shared__ u32 s[TPB];
    int t = threadIdx.x;
    int wpt = count >> 8;                              // 16 (hist) or 2 (pool)
    u32 v[16]; u32 acc = 0;
    for (int i = 0; i < wpt; i++) { v[i] = bsum[t * wpt + i]; acc += v[i]; }
    s[t] = acc; __syncthreads();
    for (int off = 1; off < TPB; off <<= 1) {          // inclusive Hillis-Steele
        u32 x = (t >= off) ? s[t - off] : 0;
        __syncthreads();
        s[t] += x;
        __syncthreads();
    }
    u32 run = s[t] - acc;                              // exclusive base
    for (int i = 0; i < wpt; i++) { bsum[t * wpt + i] = run; run += v[i]; }
}

// scan stage 3: per-entry exclusive rank into .y -----------------------------
__global__ void scan_apply_kernel(uint2* __restrict__ ent,
                                  const u32* __restrict__ bsum) {
    __shared__ u32 s[TPB];
    int t = threadIdx.x;
    size_t base = ((size_t)blockIdx.x * TPB + t) * SCAN_WPT;
    u32 pc[SCAN_WPT]; u32 acc = 0;
#pragma unroll
    for (int i = 0; i < SCAN_WPT; i++) { pc[i] = __popc(ent[base + i].x); acc += pc[i]; }
    s[t] = acc; __syncthreads();
    for (int off = 1; off < TPB; off <<= 1) {
        u32 x = (t >= off) ? s[t - off] : 0;
        __syncthreads();
        s[t] += x;
        __syncthreads();
    }
    u32 run = bsum[blockIdx.x] + s[t] - acc;
#pragma unroll
    for (int i = 0; i < SCAN_WPT; i++) { ent[base + i].y = run; run += pc[i]; }
}

// Q1: bucket histogram -------------------------------------------------------
__global__ void qcount_kernel(const int4* __restrict__ qc, int m,
                              u32* __restrict__ bcnt) {
    int p = blockIdx.x * blockDim.x + threadIdx.x;
    if (p >= m) return;
    int4 c = qc[p];
    int qk = ((c.x * 256 + c.y) * 256 + c.z) * 256 + c.w;
    atomicAdd(&bcnt[qk >> 11], 1u);
}

// Q2: exclusive scan of 16384 bucket counts, one block -----------------------
__global__ void qscan_kernel(u32* __restrict__ bcnt) {
    __shared__ u32 s[TPB];
    int t = threadIdx.x;
    const int wpt = QBUCKETS / TPB;                    // 64
    u32 v[QBUCKETS / TPB]; u32 acc = 0;
    for (int i = 0; i < wpt; i++) { v[i] = bcnt[t * wpt + i]; acc += v[i]; }
    s[t] = acc; __syncthreads();
    for (int off = 1; off < TPB; off <<= 1) {
        u32 x = (t >= off) ? s[t - off] : 0;
        __syncthreads();
        s[t] += x;
        __syncthreads();
    }
    u32 run = s[t] - acc;
    for (int i = 0; i < wpt; i++) { bcnt[t * wpt + i] = run; run += v[i]; }
}

// Q3: scatter sorted order + write head rows ---------------------------------
__global__ void qscatter_kernel(const int4* __restrict__ qc,
                                const float* __restrict__ pts,
                                int m,
                                u32* __restrict__ bcur,     // offsets -> cursors
                                u32* __restrict__ skey,
                                u32* __restrict__ perm,
                                float* __restrict__ out) {
    int p = blockIdx.x * blockDim.x + threadIdx.x;
    if (p >= m) return;
    int4 c = qc[p];
    int qk = ((c.x * 256 + c.y) * 256 + c.z) * 256 + c.w;
    u32 i = atomicAdd(&bcur[qk >> 11], 1u);
    skey[i] = (u32)qk;
    perm[i] = (u32)p;
    float4 h;                                          // head: sequential-p reads
    h.x = pts[p * 5 + 0]; h.y = pts[p * 5 + 1];
    h.z = pts[p * 5 + 2]; h.w = pts[p * 5 + 3];
    *(float4*)(out + (size_t)p * 36) = h;              // 144B rows: 16B-aligned
}

// K2: half-wave per voxel: 27-tap conv (1->32) + packed pooled write --------
__global__ void bb_pool_kernel(const int4* __restrict__ hc,
                               const int* __restrict__ hb,
                               const float* __restrict__ hf,
                               const float* __restrict__ Wbb,   // [27*32]
                               int n,
                               const uint2* __restrict__ hist_ent,
                               const uint2* __restrict__ pool_ent,
                               const u32* __restrict__ multi_bm,
                               u32* __restrict__ pooled) {
    int p = (blockIdx.x * blockDim.x + threadIdx.x) >> 5;   // voxel index
    if (p >= n) return;
    int lane = threadIdx.x & 63;
    int hb32 = lane & 32;                              // half base within wave
    int f = lane & 31;                                 // feature / tap lane

    int4 c = hc[p];
    int key = ((c.x * 256 + c.y) * 256 + c.z) * 256 + c.w;
    int pk = ((hb[p] * 256 + c.y) * 256 + c.z) * 256 + c.w;

    // pool-side loads issued early (independent of probe chain)
    uint2 pe = pool_ent[pk >> 5];
    u32 mword = multi_bm[pk >> 5];

    float fv = 0.f;
    bool hit = false;
    if (f < 27) {
        int t1 = f / 9, rem = f - t1 * 9, t2 = rem / 3, t3 = rem - t2 * 3;
        int nk = key + (t1 - 1) * 65536 + (t2 - 1) * 256 + (t3 - 1);
        uint2 e = hist_ent[nk >> 5];                   // ONE load: bits + rank
        if ((e.x >> (nk & 31)) & 1u) {
            u32 r = e.y + __popc(e.x & ((1u << (nk & 31)) - 1u));
            fv = hf[r];                                // rank == row index j
            hit = true;
        }
    }
    unsigned long long bal = __ballot(hit);
    u32 mymask = (u32)(bal >> hb32);                   // this half's hit taps

    float acc = 0.f;
    while (mymask) {
        int b = __ffs(mymask) - 1;
        mymask &= mymask - 1;
        float fb = __shfl(fv, hb32 + b);               // broadcast neighbor feat
        acc = fmaf(fb, Wbb[b * 32 + f], acc);          // L1-hot 3.4KB table
    }

    int slot = (int)(pe.y + __popc(pe.x & ((1u << (pk & 31)) - 1u)));
    bool multi = (mword >> (pk & 31)) & 1u;

    u32 tv = trans16(acc);
    u32 packed = tv | (((u32)__shfl_down((int)tv, 1)) << 16);  // pair (f, f+1)
    if ((f & 1) == 0) {
        u32* addr = pooled + (size_t)slot * 16 + (f >> 1);
        if (!multi) {
            *addr = packed;                            // ~99%: plain store
        } else {
            u32 oldv = *addr;
            while (true) {
                u32 lo = max(oldv & 0xFFFFu, packed & 0xFFFFu);
                u32 hi = max(oldv >> 16, packed >> 16);
                u32 mx = lo | (hi << 16);
                if (mx == oldv) break;
                u32 prev = atomicCAS(addr, oldv, mx);
                if (prev == oldv) break;
                oldv = prev;
            }
        }
    }
}

// K3: half-wave per SORTED query point: 27-tap conv (32->32) ----------------
__global__ void query_kernel(const u32* __restrict__ skey,
                             const u32* __restrict__ perm,
                             const float* __restrict__ Wc,       // [27][32][32]
                             int m,
                             const uint2* __restrict__ pool_ent,
                             const u16* __restrict__ pooled16,
                             float* __restrict__ out) {
    int i = (blockIdx.x * blockDim.x + threadIdx.x) >> 5;
    if (i >= m) return;
    int lane = threadIdx.x & 63;
    int hb32 = lane & 32;
    int f = lane & 31;

    int qk = (int)skey[i];                             // coalesced/broadcast
    int p  = (int)perm[i];

    int slotL = -1;
    if (f < 27) {
        int t1 = f / 9, rem = f - t1 * 9, t2 = rem / 3, t3 = rem - t2 * 3;
        int nk = qk + (t1 - 1) * 65536 + (t2 - 1) * 256 + (t3 - 1);
        uint2 e = pool_ent[nk >> 5];                   // sorted => L1/L2-hot
        if ((e.x >> (nk & 31)) & 1u)
            slotL = (int)(e.y + __popc(e.x & ((1u << (nk & 31)) - 1u)));
    }
    unsigned long long bal = __ballot(slotL >= 0);
    u32 mymask = (u32)(bal >> hb32);

    float acc = 0.f;
    while (mymask) {
        int b = __ffs(mymask) - 1;                     // tap index
        mymask &= mymask - 1;
        int slot = __shfl(slotL, hb32 + b);
        float pv = detrans16(pooled16[(size_t)slot * 32 + f]);  // 64B row
        const float* W = Wc + b * 1024 + f;            // W[b][k][f], k-major
#pragma unroll
        for (int k = 0; k < 32; k++) {
            float pk_ = __shfl(pv, hb32 + k);          // broadcast P[k]
            acc = fmaf(pk_, W[k * 32], acc);           // coalesced 128B W line
        }
    }

    out[(size_t)p * 36 + 4 + f] = acc;                 // feature row (head by Q3)
}

// ---------------------------------------------------------------------------
extern "C" void kernel_launch(void* const* d_in, const int* in_sizes, int n_in,
                              void* d_out, int out_size, void* d_ws, size_t ws_size,
                              hipStream_t stream) {
    const float* hfeat   = (const float*)d_in[0];   // [n,1]
    const float* pts     = (const float*)d_in[1];   // [m,5]
    const float* Wbb     = (const float*)d_in[2];   // [27,1,32]
    const float* Wconv   = (const float*)d_in[3];   // [27,32,32]
    const int4*  hcoords = (const int4*)d_in[4];    // [n,4] sorted by packed key
    const int*   hbatch  = (const int*)d_in[5];     // [n]
    const int4*  qcoords = (const int4*)d_in[6];    // [m,4]
    int n = in_sizes[0];
    int m = in_sizes[1] / 5;

    const int NE_H = 1 << 23;                       // 2^28 keys / 32
    const int NE_P = 1 << 20;                       // 2^25 keys / 32
    const int GB_H = NE_H / (TPB * SCAN_WPT);       // 4096
    const int GB_P = NE_P / (TPB * SCAN_WPT);       // 512

    // layout (zeroed): [pooled | hist_ent | pool_ent | multi_bm | bcnt]
    char* w = (char*)d_ws;
    char* zbase = w;
    u32* pooled       = (u32*)w;       w += (size_t)n * 64;       // 16 u32/slot
    uint2* hist_ent   = (uint2*)w;     w += (size_t)NE_H * 8;
    uint2* pool_ent   = (uint2*)w;     w += (size_t)NE_P * 8;
    u32* multi_bm     = (u32*)w;       w += (size_t)NE_P * 4;
    u32* bcnt         = (u32*)w;       w += (size_t)QBUCKETS * 4;
    size_t zbytes = (size_t)(w - zbase);
    u32* bsum_h       = (u32*)w;       w += (size_t)GB_H * 4;
    u32* bsum_p       = (u32*)w;       w += (size_t)GB_P * 4;
    u32* skey         = (u32*)w;       w += (size_t)m * 4;
    u32* perm         = (u32*)w;

    hipMemsetAsync(zbase, 0x00, zbytes, stream);

    int gb_n   = (n + TPB - 1) / TPB;
    int gb_m   = (m + TPB - 1) / TPB;
    int gb_n32 = (int)(((long long)n * 32 + TPB - 1) / TPB);
    int gb_m32 = (int)(((long long)m * 32 + TPB - 1) / TPB);

    build_bitmaps_kernel<<<gb_n, TPB, 0, stream>>>(hcoords, hbatch, n,
                                                   hist_ent, pool_ent, multi_bm);
    scan_sum_kernel<<<GB_H, TPB, 0, stream>>>(hist_ent, bsum_h);
    scan_partials_kernel<<<1, TPB, 0, stream>>>(bsum_h, GB_H);
    scan_apply_kernel<<<GB_H, TPB, 0, stream>>>(hist_ent, bsum_h);
    scan_sum_kernel<<<GB_P, TPB, 0, stream>>>(pool_ent, bsum_p);
    scan_partials_kernel<<<1, TPB, 0, stream>>>(bsum_p, GB_P);
    scan_apply_kernel<<<GB_P, TPB, 0, stream>>>(pool_ent, bsum_p);
    qcount_kernel<<<gb_m, TPB, 0, stream>>>(qcoords, m, bcnt);
    qscan_kernel<<<1, TPB, 0, stream>>>(bcnt);
    qscatter_kernel<<<gb_m, TPB, 0, stream>>>(qcoords, pts, m, bcnt,
                                              skey, perm, (float*)d_out);
    bb_pool_kernel<<<gb_n32, TPB, 0, stream>>>(hcoords, hbatch, hfeat, Wbb, n,
                                               hist_ent, pool_ent, multi_bm, pooled);
    query_kernel<<<gb_m32, TPB, 0, stream>>>(skey, perm, Wconv, m,
                                             pool_ent, (const u16*)pooled,
                                             (float*)d_out);
}

// Round 8
// 371.975 us; speedup vs baseline: 1.3370x; 1.3370x over previous
//
#include <hip/hip_runtime.h>
#include <stdint.h>

// ---------------------------------------------------------------------------
// SparseResUQueryNet: bitmap+rank sparse conv -> time max-pool -> sparse conv
//
// Round-8 = round-5 skeleton + proven deltas only:
//   - split u64 bitmap + u32 rank arrays (hist: 33.5+16.8 MB; pool: 4+2 MB,
//     L2-resident for the query kernel — r6's fused 8.4MB ent thrashed L2)
//   - probes load word AND rank unconditionally in PARALLEL (independent
//     addresses, one overlapped round-trip — fused-entry latency without
//     doubling scan/stream bytes)
//   - K2: no LDS W staging (direct L1-hot Wbb loads), early pool-side loads
//   - pooled = bf16-packed monotone u16 pairs (41MB, plain store unless multi)
//   - no query sort (r7: cost > gain)
// ---------------------------------------------------------------------------

#define TPB 256
#define SCAN_WPT 8
typedef unsigned long long u64;
typedef unsigned int u32;
typedef unsigned short u16;

// f32 -> RNE bf16 -> monotone u16 (order-preserving; 0 is below all reals)
__device__ __forceinline__ u32 trans16(float x) {
    u32 b = __float_as_uint(x);
    u32 bf = (b + 0x7FFFu + ((b >> 16) & 1u)) >> 16;
    return ((bf & 0x8000u) ? (~bf) : (bf | 0x8000u)) & 0xFFFFu;
}
__device__ __forceinline__ float detrans16(u32 u) {
    u32 orig = (u & 0x8000u) ? (u & 0x7FFFu) : ((~u) & 0xFFFFu);
    return __uint_as_float(orig << 16);
}

// K1: set existence bits; second pool contributor marks multi ----------------
__global__ void build_bitmaps_kernel(const int4* __restrict__ hc,
                                     const int* __restrict__ hb,
                                     int n,
                                     u64* __restrict__ hist_bm,
                                     u64* __restrict__ pool_bm,
                                     u64* __restrict__ multi_bm) {
    int j = blockIdx.x * blockDim.x + threadIdx.x;
    if (j >= n) return;
    int4 c = hc[j];                                   // (t,x,y,z)
    int key = ((c.x * 256 + c.y) * 256 + c.z) * 256 + c.w;
    atomicOr(&hist_bm[key >> 6], 1ull << (key & 63));
    int pk = ((hb[j] * 256 + c.y) * 256 + c.z) * 256 + c.w;
    u64 bit = 1ull << (pk & 63);
    u64 old = atomicOr(&pool_bm[pk >> 6], bit);
    if (old & bit) atomicOr(&multi_bm[pk >> 6], bit); // >=2 contributors
}

// scan stage 1: per-block popcount sums --------------------------------------
__global__ void scan_sum_kernel(const u64* __restrict__ bm, u32* __restrict__ bsum) {
    __shared__ u32 s[TPB];
    int t = threadIdx.x;
    size_t base = ((size_t)blockIdx.x * TPB + t) * SCAN_WPT;
    u32 acc = 0;
#pragma unroll
    for (int i = 0; i < SCAN_WPT; i++) acc += __popcll(bm[base + i]);
    s[t] = acc; __syncthreads();
    for (int off = TPB / 2; off > 0; off >>= 1) {
        if (t < off) s[t] += s[t + off];
        __syncthreads();
    }
    if (t == 0) bsum[blockIdx.x] = s[0];
}

// scan stage 2: exclusive scan of block sums (count <= 2048), one block ------
__global__ void scan_partials_kernel(u32* __restrict__ bsum, int count) {
    __shared__ u32 s[TPB];
    int t = threadIdx.x;
    int wpt = count >> 8;                              // 8 (hist) or 1 (pool)
    u32 v[8]; u32 acc = 0;
    for (int i = 0; i < wpt; i++) { v[i] = bsum[t * wpt + i]; acc += v[i]; }
    s[t] = acc; __syncthreads();
    for (int off = 1; off < TPB; off <<= 1) {          // inclusive Hillis-Steele
        u32 x = (t >= off) ? s[t - off] : 0;
        __syncthreads();
        s[t] += x;
        __syncthreads();
    }
    u32 run = s[t] - acc;                              // exclusive base
    for (int i = 0; i < wpt; i++) { bsum[t * wpt + i] = run; run += v[i]; }
}

// scan stage 3: per-word exclusive rank --------------------------------------
__global__ void scan_apply_kernel(const u64* __restrict__ bm,
                                  const u32* __restrict__ bsum,
                                  u32* __restrict__ rank) {
    __shared__ u32 s[TPB];
    int t = threadIdx.x;
    size_t base = ((size_t)blockIdx.x * TPB + t) * SCAN_WPT;
    u32 pc[SCAN_WPT]; u32 acc = 0;
#pragma unroll
    for (int i = 0; i < SCAN_WPT; i++) { pc[i] = __popcll(bm[base + i]); acc += pc[i]; }
    s[t] = acc; __syncthreads();
    for (int off = 1; off < TPB; off <<= 1) {
        u32 x = (t >= off) ? s[t - off] : 0;
        __syncthreads();
        s[t] += x;
        __syncthreads();
    }
    u32 run = bsum[blockIdx.x] + s[t] - acc;
#pragma unroll
    for (int i = 0; i < SCAN_WPT; i++) { rank[base + i] = run; run += pc[i]; }
}

// K2: half-wave per voxel: 27-tap conv (1->32) + packed pooled write --------
__global__ void bb_pool_kernel(const int4* __restrict__ hc,
                               const int* __restrict__ hb,
                               const float* __restrict__ hf,
                               const float* __restrict__ Wbb,   // [27*32]
                               int n,
                               const u64* __restrict__ hist_bm,
                               const u32* __restrict__ hist_rank,
                               const u64* __restrict__ pool_bm,
                               const u32* __restrict__ pool_rank,
                               const u64* __restrict__ multi_bm,
                               u32* __restrict__ pooled) {
    int p = (blockIdx.x * blockDim.x + threadIdx.x) >> 5;   // voxel index
    if (p >= n) return;
    int lane = threadIdx.x & 63;
    int hb32 = lane & 32;                              // half base within wave
    int f = lane & 31;                                 // feature / tap lane

    int4 c = hc[p];
    int key = ((c.x * 256 + c.y) * 256 + c.z) * 256 + c.w;
    int pk = ((hb[p] * 256 + c.y) * 256 + c.z) * 256 + c.w;

    // pool-side loads issued early (independent of probe chain)
    u64 pword = pool_bm[pk >> 6];
    u32 prank = pool_rank[pk >> 6];
    u64 mword = multi_bm[pk >> 6];

    float fv = 0.f;
    bool hit = false;
    if (f < 27) {
        int t1 = f / 9, rem = f - t1 * 9, t2 = rem / 3, t3 = rem - t2 * 3;
        int nk = key + (t1 - 1) * 65536 + (t2 - 1) * 256 + (t3 - 1);
        u64 word = hist_bm[nk >> 6];                   // parallel independent
        u32 rk   = hist_rank[nk >> 6];                 // loads (overlapped)
        if ((word >> (nk & 63)) & 1ull) {
            u32 r = rk + (u32)__popcll(word & ((1ull << (nk & 63)) - 1ull));
            fv = hf[r];                                // rank == row index j
            hit = true;
        }
    }
    unsigned long long bal = __ballot(hit);
    u32 mymask = (u32)(bal >> hb32);                   // this half's hit taps

    float acc = 0.f;
    while (mymask) {
        int b = __ffs(mymask) - 1;
        mymask &= mymask - 1;
        float fb = __shfl(fv, hb32 + b);               // broadcast neighbor feat
        acc = fmaf(fb, Wbb[b * 32 + f], acc);          // L1-hot 3.4KB table
    }

    int bit = pk & 63;
    int slot = (int)(prank + (u32)__popcll(pword & ((1ull << bit) - 1ull)));
    bool multi = (mword >> bit) & 1ull;

    u32 tv = trans16(acc);
    u32 packed = tv | (((u32)__shfl_down((int)tv, 1)) << 16);  // pair (f, f+1)
    if ((f & 1) == 0) {
        u32* addr = pooled + (size_t)slot * 16 + (f >> 1);
        if (!multi) {
            *addr = packed;                            // ~99%: plain store
        } else {
            u32 oldv = *addr;
            while (true) {
                u32 lo = max(oldv & 0xFFFFu, packed & 0xFFFFu);
                u32 hi = max(oldv >> 16, packed >> 16);
                u32 mx = lo | (hi << 16);
                if (mx == oldv) break;
                u32 prev = atomicCAS(addr, oldv, mx);
                if (prev == oldv) break;
                oldv = prev;
            }
        }
    }
}

// K3: half-wave per query point: 27-tap conv (32->32) + output --------------
__global__ void query_kernel(const int4* __restrict__ qc,
                             const float* __restrict__ pts,      // stride 5
                             const float* __restrict__ Wc,       // [27][32][32]
                             int m,
                             const u64* __restrict__ pool_bm,
                             const u32* __restrict__ pool_rank,
                             const u16* __restrict__ pooled16,
                             float* __restrict__ out) {
    int p = (blockIdx.x * blockDim.x + threadIdx.x) >> 5;
    if (p >= m) return;
    int lane = threadIdx.x & 63;
    int hb32 = lane & 32;
    int f = lane & 31;

    int4 c = qc[p];                                    // (b,x,y,z)
    int qk = ((c.x * 256 + c.y) * 256 + c.z) * 256 + c.w;

    int slotL = -1;
    if (f < 27) {
        int t1 = f / 9, rem = f - t1 * 9, t2 = rem / 3, t3 = rem - t2 * 3;
        int nk = qk + (t1 - 1) * 65536 + (t2 - 1) * 256 + (t3 - 1);
        u64 word = pool_bm[nk >> 6];                   // 4MB, L2-resident
        u32 rk   = pool_rank[nk >> 6];                 // 2MB, parallel load
        if ((word >> (nk & 63)) & 1ull)
            slotL = (int)(rk + (u32)__popcll(word & ((1ull << (nk & 63)) - 1ull)));
    }
    unsigned long long bal = __ballot(slotL >= 0);
    u32 mymask = (u32)(bal >> hb32);

    float acc = 0.f;
    while (mymask) {
        int b = __ffs(mymask) - 1;                     // tap index
        mymask &= mymask - 1;
        int slot = __shfl(slotL, hb32 + b);
        float pv = detrans16(pooled16[(size_t)slot * 32 + f]);  // 64B row
        const float* W = Wc + b * 1024 + f;            // W[b][k][f], k-major
#pragma unroll
        for (int k = 0; k < 32; k++) {
            float pk_ = __shfl(pv, hb32 + k);          // broadcast P[k]
            acc = fmaf(pk_, W[k * 32], acc);           // coalesced 128B W line
        }
    }

    out[(size_t)p * 36 + 4 + f] = acc;                 // features, coalesced
    if (f < 4) out[(size_t)p * 36 + f] = pts[p * 5 + f];  // head
}

// ---------------------------------------------------------------------------
extern "C" void kernel_launch(void* const* d_in, const int* in_sizes, int n_in,
                              void* d_out, int out_size, void* d_ws, size_t ws_size,
                              hipStream_t stream) {
    const float* hfeat   = (const float*)d_in[0];   // [n,1]
    const float* pts     = (const float*)d_in[1];   // [m,5]
    const float* Wbb     = (const float*)d_in[2];   // [27,1,32]
    const float* Wconv   = (const float*)d_in[3];   // [27,32,32]
    const int4*  hcoords = (const int4*)d_in[4];    // [n,4] sorted by packed key
    const int*   hbatch  = (const int*)d_in[5];     // [n]
    const int4*  qcoords = (const int4*)d_in[6];    // [m,4]
    int n = in_sizes[0];
    int m = in_sizes[1] / 5;

    const int NW_H = 1 << 22;                       // 2^28 bits / 64
    const int NW_P = 1 << 19;                       // 2^25 bits / 64
    const int GB_H = NW_H / (TPB * SCAN_WPT);       // 2048
    const int GB_P = NW_P / (TPB * SCAN_WPT);       // 256

    // layout: [pooled | hist_bm | pool_bm | multi_bm] zeroed; ranks after
    char* w = (char*)d_ws;
    char* zbase = w;
    u32* pooled       = (u32*)w;       w += (size_t)n * 64;      // 16 u32/slot
    u64* hist_bm      = (u64*)w;       w += (size_t)NW_H * 8;
    u64* pool_bm      = (u64*)w;       w += (size_t)NW_P * 8;
    u64* multi_bm     = (u64*)w;       w += (size_t)NW_P * 8;
    size_t zbytes = (size_t)(w - zbase);
    u32* hist_rank    = (u32*)w;       w += (size_t)NW_H * 4;
    u32* pool_rank    = (u32*)w;       w += (size_t)NW_P * 4;
    u32* bsum_h       = (u32*)w;       w += (size_t)GB_H * 4;
    u32* bsum_p       = (u32*)w;

    hipMemsetAsync(zbase, 0x00, zbytes, stream);

    int gb_n   = (n + TPB - 1) / TPB;
    int gb_n32 = (int)(((long long)n * 32 + TPB - 1) / TPB);
    int gb_m32 = (int)(((long long)m * 32 + TPB - 1) / TPB);

    build_bitmaps_kernel<<<gb_n, TPB, 0, stream>>>(hcoords, hbatch, n,
                                                   hist_bm, pool_bm, multi_bm);
    scan_sum_kernel<<<GB_H, TPB, 0, stream>>>(hist_bm, bsum_h);
    scan_partials_kernel<<<1, TPB, 0, stream>>>(bsum_h, GB_H);
    scan_apply_kernel<<<GB_H, TPB, 0, stream>>>(hist_bm, bsum_h, hist_rank);
    scan_sum_kernel<<<GB_P, TPB, 0, stream>>>(pool_bm, bsum_p);
    scan_partials_kernel<<<1, TPB, 0, stream>>>(bsum_p, GB_P);
    scan_apply_kernel<<<GB_P, TPB, 0, stream>>>(pool_bm, bsum_p, pool_rank);
    bb_pool_kernel<<<gb_n32, TPB, 0, stream>>>(hcoords, hbatch, hfeat, Wbb, n,
                                               hist_bm, hist_rank,
                                               pool_bm, pool_rank, multi_bm, pooled);
    query_kernel<<<gb_m32, TPB, 0, stream>>>(qcoords, pts, Wconv, m,
                                             pool_bm, pool_rank,
                                             (const u16*)pooled, (float*)d_out);
}